// Round 1
// baseline (336.461 us; speedup 1.0000x reference)
//
#include <hip/hip_runtime.h>
#include <math.h>

#define B_ 4
#define N_ 2048
#define M_ 4096

// ---- constants (fp32 copies of the reference's) ----
__constant__ float c_LO[10] = {0.0f, 0.00794435329f, 0.0158887021f, 0.0238330509f,
                               0.0317773996f, 0.0397217484f, 0.0476660972f,
                               0.0556104459f, 0.0635547947f, 0.0714991435f};
__constant__ float c_HI[10] = {0.00794435329f, 0.0158887021f, 0.0238330509f,
                               0.0317773996f, 0.0397217484f, 0.0476660972f,
                               0.0556104459f, 0.0635547947f, 0.0714991435f, 0.08f};
__constant__ float c_BW[10] = {0.16652107f, 0.21488856f, 0.37031708f, 0.55618503f,
                               0.75124664f, 0.93943357f, 1.07824539f, 1.19423112f,
                               1.55731375f, 2.34173634f};

#define R2_ 2.5e-05f   // fp32(0.005**2 computed in double) — matches JAX weak-type cast
#define FAR_ 100000.0f
#define EPS_ 1e-07f

// ---------------------------------------------------------------------------
// JAX threefry2x32, key = jax.random.key(42) -> (0, 42)
__device__ inline unsigned rotl32(unsigned x, int d) { return (x << d) | (x >> (32 - d)); }

__device__ inline void threefry2x32_42(unsigned x0, unsigned x1, unsigned& o0, unsigned& o1) {
    const unsigned k0 = 0u, k1 = 42u;
    const unsigned k2 = k0 ^ k1 ^ 0x1BD11BDAu;
    const unsigned ks[3] = {k0, k1, k2};
    const int rot[2][4] = {{13, 15, 26, 6}, {17, 29, 16, 24}};
    unsigned v0 = x0 + k0;
    unsigned v1 = x1 + k1;
#pragma unroll
    for (int i = 0; i < 5; ++i) {
        const int* r = rot[i & 1];
#pragma unroll
        for (int j = 0; j < 4; ++j) {
            v0 += v1;
            v1 = rotl32(v1, r[j]);
            v1 ^= v0;
        }
        v0 += ks[(i + 1) % 3];
        v1 += ks[(i + 2) % 3] + (unsigned)(i + 1);
    }
    o0 = v0; o1 = v1;
}

__device__ inline float bits_to_uniform(unsigned bits) {
    float f = __uint_as_float((bits >> 9) | 0x3f800000u) - 1.0f;
    return fmaxf(0.0f, f);
}

// r[b,n] for flat index i in [0, 8192): counts split (i, i+4096)
__device__ inline float jax_uniform_r(int flat) {
    unsigned o0, o1;
    if (flat < 4096) {
        threefry2x32_42((unsigned)flat, (unsigned)(flat + 4096), o0, o1);
        return bits_to_uniform(o0);
    } else {
        threefry2x32_42((unsigned)(flat - 4096), (unsigned)flat, o0, o1);
        return bits_to_uniform(o1);
    }
}

// ---------------------------------------------------------------------------
// Kernel 0: pack contact points -> float4 {x,y,z,|q|^2}
__global__ void pack_contacts(const float* __restrict__ pts, float4* __restrict__ out) {
    int i = blockIdx.x * blockDim.x + threadIdx.x;
    if (i >= B_ * M_) return;
    float x = pts[(size_t)i * 3 + 0];
    float y = pts[(size_t)i * 3 + 1];
    float z = pts[(size_t)i * 3 + 2];
    out[i] = make_float4(x, y, z, x * x + y * y + z * z);
}

// ---------------------------------------------------------------------------
// Kernel 1: nearest contact per pred point. Block = 32 points x 8 M-partitions.
__global__ void nn_kernel(const float* __restrict__ ppts, const float4* __restrict__ cpk,
                          int* __restrict__ idx_out, float* __restrict__ d2_out) {
    int blk = blockIdx.x;                 // B * (N/32)
    int b = blk / (N_ / 32);
    int chunk = blk % (N_ / 32);
    int p = threadIdx.x & 31;
    int part = threadIdx.x >> 5;          // 0..7
    int n = chunk * 32 + p;
    const float* pp = ppts + ((size_t)b * N_ + n) * 3;
    float ax = pp[0], ay = pp[1], az = pp[2];
    float an = ax * ax + ay * ay + az * az;
    const float4* cb = cpk + (size_t)b * M_;

    int j0 = part * (M_ / 8);
    float best = INFINITY;
    int bidx = 0;
    for (int j = j0; j < j0 + (M_ / 8); ++j) {
        float4 q = cb[j];
        float cross = ax * q.x + ay * q.y + az * q.z;
        float d = an + q.w - 2.0f * cross;
        d = fmaxf(d, 0.0f);
        if (d < best) { best = d; bidx = j; }   // strict < keeps first occurrence
    }
    __shared__ float sd[256];
    __shared__ int si[256];
    sd[threadIdx.x] = best;
    si[threadIdx.x] = bidx;
    __syncthreads();
    if (part == 0) {
        for (int q = 1; q < 8; ++q) {
            float dv = sd[q * 32 + p];
            if (dv < best) { best = dv; bidx = si[q * 32 + p]; }  // later parts have larger idx
        }
        idx_out[b * N_ + n] = bidx;
        d2_out[b * N_ + n] = best;
    }
}

// ---------------------------------------------------------------------------
// Kernel 2: build P (pred control points) and G/Gs (label control points, FAR if fail)
__global__ void prep_kernel(const float* __restrict__ pred_grasps,
                            const int* __restrict__ idxw, const float* __restrict__ d2w,
                            const float* __restrict__ rot, const float* __restrict__ trans,
                            const float* __restrict__ cp, const float* __restrict__ cps,
                            float* __restrict__ Pout, float* __restrict__ Gout) {
    int i = blockIdx.x * blockDim.x + threadIdx.x;   // 0..B*N-1
    if (i >= B_ * N_) return;
    int b = i >> 11;

    const float* g = pred_grasps + (size_t)i * 16;
    float R[3][3] = {{g[0], g[1], g[2]}, {g[4], g[5], g[6]}, {g[8], g[9], g[10]}};
    float t[3] = {g[3], g[7], g[11]};

    float* P = Pout + (size_t)i * 16;
    float pn = 0.0f;
#pragma unroll
    for (int c = 0; c < 5; ++c) {
        float cx = cp[c * 3], cy = cp[c * 3 + 1], cz = cp[c * 3 + 2];
#pragma unroll
        for (int ii = 0; ii < 3; ++ii) {
            float v = R[ii][0] * cx + R[ii][1] * cy + R[ii][2] * cz + t[ii];
            P[c * 3 + ii] = v;
            pn += v * v;
        }
    }
    P[15] = pn;

    bool succ = d2w[i] < R2_;
    int j = idxw[i];
    float RL[3][3], TL[3];
    if (succ) {
        const float* rl = rot + ((size_t)b * M_ + j) * 9;
#pragma unroll
        for (int a = 0; a < 3; ++a)
#pragma unroll
            for (int bb = 0; bb < 3; ++bb) RL[a][bb] = rl[a * 3 + bb];
        const float* tl = trans + ((size_t)b * M_ + j) * 3;
        TL[0] = tl[0]; TL[1] = tl[1]; TL[2] = tl[2];
    } else {
#pragma unroll
        for (int a = 0; a < 3; ++a) {
#pragma unroll
            for (int bb = 0; bb < 3; ++bb) RL[a][bb] = FAR_;
            TL[a] = FAR_;
        }
    }

    float* G = Gout + (size_t)i * 32;
    float gn = 0.0f, gsn = 0.0f;
#pragma unroll
    for (int c = 0; c < 5; ++c) {
        float cx = cp[c * 3], cy = cp[c * 3 + 1], cz = cp[c * 3 + 2];
#pragma unroll
        for (int ii = 0; ii < 3; ++ii) {
            float v = RL[ii][0] * cx + RL[ii][1] * cy + RL[ii][2] * cz + TL[ii];
            G[c * 3 + ii] = v;
            gn += v * v;
        }
    }
    G[15] = gn;
#pragma unroll
    for (int c = 0; c < 5; ++c) {
        float cx = cps[c * 3], cy = cps[c * 3 + 1], cz = cps[c * 3 + 2];
#pragma unroll
        for (int ii = 0; ii < 3; ++ii) {
            float v = RL[ii][0] * cx + RL[ii][1] * cy + RL[ii][2] * cz + TL[ii];
            G[16 + c * 3 + ii] = v;
            gsn += v * v;
        }
    }
    G[31] = gsn;
}

// ---------------------------------------------------------------------------
// Kernel 3: ADD-S min: m[b,i] = min_j min(|P_i - G_j|^2, |P_i - Gs_j|^2)
// Block = 32 i x 8 j-partitions (256 j each).
__global__ void adds_kernel(const float* __restrict__ Parr, const float* __restrict__ Garr,
                            float* __restrict__ mOut) {
    int blk = blockIdx.x;                  // B * (N/32)
    int b = blk / (N_ / 32);
    int chunk = blk % (N_ / 32);
    int p = threadIdx.x & 31;
    int part = threadIdx.x >> 5;
    int i = chunk * 32 + p;

    const float4* P4 = reinterpret_cast<const float4*>(Parr) + ((size_t)b * N_ + i) * 4;
    float Pv[16];
#pragma unroll
    for (int q = 0; q < 4; ++q) {
        float4 t4 = P4[q];
        Pv[q * 4 + 0] = t4.x; Pv[q * 4 + 1] = t4.y; Pv[q * 4 + 2] = t4.z; Pv[q * 4 + 3] = t4.w;
    }
    float pn = Pv[15];

    const float4* Gb = reinterpret_cast<const float4*>(Garr) + (size_t)b * N_ * 8;
    float best = INFINITY;
    int j0 = part * (N_ / 8);
    for (int j = j0; j < j0 + (N_ / 8); ++j) {
        const float4* G4 = Gb + (size_t)j * 8;
        float gg[32];
#pragma unroll
        for (int q = 0; q < 8; ++q) {
            float4 t4 = G4[q];
            gg[q * 4 + 0] = t4.x; gg[q * 4 + 1] = t4.y; gg[q * 4 + 2] = t4.z; gg[q * 4 + 3] = t4.w;
        }
        float d1 = 0.0f, d2v = 0.0f;
#pragma unroll
        for (int q = 0; q < 15; ++q) d1 += Pv[q] * gg[q];
#pragma unroll
        for (int q = 0; q < 15; ++q) d2v += Pv[q] * gg[16 + q];
        float s1 = pn + gg[15] - 2.0f * d1;
        float s2 = pn + gg[31] - 2.0f * d2v;
        best = fminf(best, fminf(s1, s2));
    }
    __shared__ float sm[256];
    sm[threadIdx.x] = best;
    __syncthreads();
    if (part == 0) {
#pragma unroll
        for (int q = 1; q < 8; ++q) best = fminf(best, sm[q * 32 + p]);
        mOut[b * N_ + i] = best;
    }
}

// ---------------------------------------------------------------------------
// Kernel 4: per-batch finalize — threefry r, hard-negative selection, all sums.
__global__ void finalize_kernel(const float* __restrict__ scores,
                                const float* __restrict__ gwh,
                                const float* __restrict__ pcw,
                                const int* __restrict__ idxw,
                                const float* __restrict__ d2w,
                                const float* __restrict__ mw,
                                float* __restrict__ batch_out) {
    int b = blockIdx.x;
    int tid = threadIdx.x;

    __shared__ float r_sh[N_];
    __shared__ float rlist[N_];
    __shared__ short neglist[N_];
    __shared__ unsigned char pos_sh[N_];
    __shared__ unsigned char sel_sh[N_];
    __shared__ int s_npos, s_ncnt;
    __shared__ float wsum[4][4];

    if (tid == 0) { s_npos = 0; s_ncnt = 0; }
    __syncthreads();

    int local_pos = 0;
    for (int n = tid; n < N_; n += 256) {
        bool pos = d2w[b * N_ + n] < R2_;
        pos_sh[n] = pos ? 1 : 0;
        sel_sh[n] = pos ? 1 : 0;
        float rr = jax_uniform_r(b * N_ + n);
        r_sh[n] = rr;
        if (pos) {
            local_pos++;
        } else {
            int a = atomicAdd(&s_ncnt, 1);
            neglist[a] = (short)n;
            rlist[a] = rr;
        }
    }
    atomicAdd(&s_npos, local_pos);
    __syncthreads();

    int npos = s_npos;
    int ncnt = s_ncnt;
    int kk = (npos > 0) ? npos : 2;

    // rank each negative among negatives by r (stable tie-break on index)
    for (int a = tid; a < ncnt; a += 256) {
        float ra = rlist[a];
        int na = neglist[a];
        int cnt = 0;
        for (int q = 0; q < ncnt; ++q) {
            float rb = rlist[q];
            int nb = neglist[q];
            cnt += ((rb < ra) || (rb == ra && nb < na)) ? 1 : 0;
        }
        if (cnt < kk) sel_sh[na] = 1;
    }
    __syncthreads();

    float sum_sel = 0.0f, sum_bce = 0.0f, sum_wl = 0.0f, sum_adds = 0.0f;
    for (int n = tid; n < N_; n += 256) {
        float sc = scores[b * N_ + n];
        float pcl = fminf(fmaxf(sc, EPS_), 0.9999999f);
        bool pos = pos_sh[n] != 0;
        float s = pos ? 1.0f : 0.0f;
        float bce = -(s * logf(pcl) + (1.0f - s) * logf(1.0f - pcl));
        float selv = sel_sh[n] ? 1.0f : 0.0f;
        sum_sel += selv;
        sum_bce += bce * selv;
        if (pos) {
            int jx = idxw[b * N_ + n];
            float w = pcw[b * M_ + jx];
            float acc = 0.0f;
#pragma unroll
            for (int jb = 0; jb < 10; ++jb) {
                float x = gwh[((size_t)b * 10 + jb) * N_ + n];
                float mh = (w >= c_LO[jb] && w < c_HI[jb]) ? 1.0f : 0.0f;
                float bw = fmaxf(x, 0.0f) - x * mh + log1pf(expf(-fabsf(x)));
                acc += c_BW[jb] * bw;
            }
            sum_wl += acc * 0.1f;
            float mv = mw[b * N_ + n];
            sum_adds += sc * sqrtf(fmaxf(mv, 0.0f) + 1e-12f);
        }
    }

    // deterministic reduce: wave shuffle + per-wave LDS + thread-0 combine
    float v0 = sum_sel, v1 = sum_bce, v2 = sum_wl, v3 = sum_adds;
#pragma unroll
    for (int off = 32; off > 0; off >>= 1) {
        v0 += __shfl_down(v0, off);
        v1 += __shfl_down(v1, off);
        v2 += __shfl_down(v2, off);
        v3 += __shfl_down(v3, off);
    }
    int wv = tid >> 6, lane = tid & 63;
    if (lane == 0) { wsum[wv][0] = v0; wsum[wv][1] = v1; wsum[wv][2] = v2; wsum[wv][3] = v3; }
    __syncthreads();
    if (tid == 0) {
        float t0 = 0, t1 = 0, t2 = 0, t3 = 0;
#pragma unroll
        for (int w = 0; w < 4; ++w) { t0 += wsum[w][0]; t1 += wsum[w][1]; t2 += wsum[w][2]; t3 += wsum[w][3]; }
        float piv = fmaxf((float)npos, 1.0f);       // pos_in_view
        float bin_ce_b = t1 / fmaxf(t0, 1.0f);
        float width_b = t2 / piv;
        float adds_b = t3 / piv;
        batch_out[b * 3 + 0] = bin_ce_b;
        batch_out[b * 3 + 1] = width_b;
        batch_out[b * 3 + 2] = adds_b;
    }
}

// ---------------------------------------------------------------------------
// Kernel 5: combine batches -> 4 outputs
__global__ void combine_kernel(const float* __restrict__ bv, float* __restrict__ out) {
    if (blockIdx.x == 0 && threadIdx.x == 0) {
        float bin = 0, wid = 0, ad = 0;
#pragma unroll
        for (int b = 0; b < B_; ++b) {
            bin += bv[b * 3 + 0];
            wid += bv[b * 3 + 1];
            ad += bv[b * 3 + 2];
        }
        bin *= 0.25f; wid *= 0.25f; ad *= 0.25f;
        out[0] = bin + wid + 3.0f * ad;
        out[1] = bin;
        out[2] = wid;
        out[3] = ad;
    }
}

// ---------------------------------------------------------------------------
extern "C" void kernel_launch(void* const* d_in, const int* in_sizes, int n_in,
                              void* d_out, int out_size, void* d_ws, size_t ws_size,
                              hipStream_t stream) {
    const float* pred_grasps = (const float*)d_in[0];   // (4,2048,4,4)
    const float* pred_scores = (const float*)d_in[1];   // (4,2048,1)
    const float* pred_points = (const float*)d_in[2];   // (4,2048,3)
    const float* gwh         = (const float*)d_in[3];   // (4,10,2048)
    const float* pcp         = (const float*)d_in[4];   // (4,4096,3)
    const float* pcw         = (const float*)d_in[5];   // (4,4096)
    const float* pcr         = (const float*)d_in[6];   // (4,4096,3,3)
    const float* pct         = (const float*)d_in[7];   // (4,4096,3)
    const float* cp          = (const float*)d_in[8];   // (1,5,3)
    const float* cps         = (const float*)d_in[9];   // (1,5,3)
    (void)in_sizes; (void)n_in; (void)out_size; (void)ws_size;

    float* ws = (float*)d_ws;
    float4* cpack = (float4*)ws;                        //  65536 floats
    int*   idxw = (int*)(ws + 65536);                   //   8192
    float* d2w  = ws + 65536 + 8192;                    //   8192
    float* Pw   = ws + 65536 + 16384;                   // 131072
    float* Gw   = Pw + 131072;                          // 262144
    float* mw   = Gw + 262144;                          //   8192
    float* bv   = mw + 8192;                            //     12
    float* outp = (float*)d_out;

    hipLaunchKernelGGL(pack_contacts, dim3((B_ * M_ + 255) / 256), dim3(256), 0, stream,
                       pcp, cpack);
    hipLaunchKernelGGL(nn_kernel, dim3(B_ * (N_ / 32)), dim3(256), 0, stream,
                       pred_points, cpack, idxw, d2w);
    hipLaunchKernelGGL(prep_kernel, dim3((B_ * N_ + 255) / 256), dim3(256), 0, stream,
                       pred_grasps, idxw, d2w, pcr, pct, cp, cps, Pw, Gw);
    hipLaunchKernelGGL(adds_kernel, dim3(B_ * (N_ / 32)), dim3(256), 0, stream,
                       Pw, Gw, mw);
    hipLaunchKernelGGL(finalize_kernel, dim3(B_), dim3(256), 0, stream,
                       pred_scores, gwh, pcw, idxw, d2w, mw, bv);
    hipLaunchKernelGGL(combine_kernel, dim3(1), dim3(64), 0, stream, bv, outp);
}

// Round 2
// 235.464 us; speedup vs baseline: 1.4289x; 1.4289x over previous
//
#include <hip/hip_runtime.h>
#include <math.h>

#define B_ 4
#define N_ 2048
#define M_ 4096

// ---- constants (fp32 copies of the reference's) ----
__constant__ float c_LO[10] = {0.0f, 0.00794435329f, 0.0158887021f, 0.0238330509f,
                               0.0317773996f, 0.0397217484f, 0.0476660972f,
                               0.0556104459f, 0.0635547947f, 0.0714991435f};
__constant__ float c_HI[10] = {0.00794435329f, 0.0158887021f, 0.0238330509f,
                               0.0317773996f, 0.0397217484f, 0.0476660972f,
                               0.0556104459f, 0.0635547947f, 0.0714991435f, 0.08f};
__constant__ float c_BW[10] = {0.16652107f, 0.21488856f, 0.37031708f, 0.55618503f,
                               0.75124664f, 0.93943357f, 1.07824539f, 1.19423112f,
                               1.55731375f, 2.34173634f};

#define R2_ 2.5e-05f   // fp32(0.005**2) — matches JAX weak-type cast
#define FAR_ 100000.0f
#define EPS_ 1e-07f

// ---------------------------------------------------------------------------
// JAX threefry2x32, key = jax.random.key(42) -> (0, 42)
__device__ inline unsigned rotl32(unsigned x, int d) { return (x << d) | (x >> (32 - d)); }

__device__ inline void threefry2x32_42(unsigned x0, unsigned x1, unsigned& o0, unsigned& o1) {
    const unsigned k0 = 0u, k1 = 42u;
    const unsigned k2 = k0 ^ k1 ^ 0x1BD11BDAu;
    const unsigned ks[3] = {k0, k1, k2};
    const int rot[2][4] = {{13, 15, 26, 6}, {17, 29, 16, 24}};
    unsigned v0 = x0 + k0;
    unsigned v1 = x1 + k1;
#pragma unroll
    for (int i = 0; i < 5; ++i) {
        const int* r = rot[i & 1];
#pragma unroll
        for (int j = 0; j < 4; ++j) {
            v0 += v1;
            v1 = rotl32(v1, r[j]);
            v1 ^= v0;
        }
        v0 += ks[(i + 1) % 3];
        v1 += ks[(i + 2) % 3] + (unsigned)(i + 1);
    }
    o0 = v0; o1 = v1;
}

__device__ inline float bits_to_uniform(unsigned bits) {
    float f = __uint_as_float((bits >> 9) | 0x3f800000u) - 1.0f;
    return fmaxf(0.0f, f);
}

__device__ inline float jax_uniform_r(int flat) {
    unsigned o0, o1;
    if (flat < 4096) {
        threefry2x32_42((unsigned)flat, (unsigned)(flat + 4096), o0, o1);
        return bits_to_uniform(o0);
    } else {
        threefry2x32_42((unsigned)(flat - 4096), (unsigned)flat, o0, o1);
        return bits_to_uniform(o1);
    }
}

// ---------------------------------------------------------------------------
// Kernel 0: pack contact points -> float4 {x,y,z,|q|^2}
__global__ void pack_contacts(const float* __restrict__ pts, float4* __restrict__ out) {
    int i = blockIdx.x * blockDim.x + threadIdx.x;
    if (i >= B_ * M_) return;
    float x = pts[(size_t)i * 3 + 0];
    float y = pts[(size_t)i * 3 + 1];
    float z = pts[(size_t)i * 3 + 2];
    out[i] = make_float4(x, y, z, x * x + y * y + z * z);
}

// ---------------------------------------------------------------------------
// Kernel 1: nearest contact per pred point.
// Grid = B * (N/8) = 1024 blocks. Block = 8 points x 32 M-partitions (128 j each).
__global__ void nn_kernel(const float* __restrict__ ppts, const float4* __restrict__ cpk,
                          int* __restrict__ idx_out, float* __restrict__ d2_out) {
    int blk = blockIdx.x;                 // B * (N/8)
    int b = blk / (N_ / 8);
    int tile = blk % (N_ / 8);
    int p = threadIdx.x & 7;              // i within tile
    int part = threadIdx.x >> 3;          // 0..31 (j partition, ascending j)
    int n = tile * 8 + p;
    const float* pp = ppts + ((size_t)b * N_ + n) * 3;
    float ax = pp[0], ay = pp[1], az = pp[2];
    float an = ax * ax + ay * ay + az * az;
    const float4* cb = cpk + (size_t)b * M_;

    int j0 = part * (M_ / 32);
    float best = INFINITY;
    int bidx = 0;
    for (int j = j0; j < j0 + (M_ / 32); ++j) {
        float4 q = cb[j];
        float cross = ax * q.x + ay * q.y + az * q.z;
        float d = an + q.w - 2.0f * cross;
        d = fmaxf(d, 0.0f);
        if (d < best) { best = d; bidx = j; }   // strict < keeps first occurrence
    }
    __shared__ float sd[256];
    __shared__ int si[256];
    sd[part * 8 + p] = best;
    si[part * 8 + p] = bidx;
    __syncthreads();
    if (threadIdx.x < 8) {
        int pp2 = threadIdx.x;
        float bb = sd[pp2];
        int bi = si[pp2];
        for (int q = 1; q < 32; ++q) {          // ascending part == ascending j
            float dv = sd[q * 8 + pp2];
            if (dv < bb) { bb = dv; bi = si[q * 8 + pp2]; }
        }
        idx_out[b * N_ + tile * 8 + pp2] = bi;
        d2_out[b * N_ + tile * 8 + pp2] = bb;
    }
}

// ---------------------------------------------------------------------------
// Kernel 2: build P (pred control points) and G/Gs (label control points, FAR if fail)
__global__ void prep_kernel(const float* __restrict__ pred_grasps,
                            const int* __restrict__ idxw, const float* __restrict__ d2w,
                            const float* __restrict__ rot, const float* __restrict__ trans,
                            const float* __restrict__ cp, const float* __restrict__ cps,
                            float* __restrict__ Pout, float* __restrict__ Gout) {
    int i = blockIdx.x * blockDim.x + threadIdx.x;   // 0..B*N-1
    if (i >= B_ * N_) return;
    int b = i >> 11;

    const float* g = pred_grasps + (size_t)i * 16;
    float R[3][3] = {{g[0], g[1], g[2]}, {g[4], g[5], g[6]}, {g[8], g[9], g[10]}};
    float t[3] = {g[3], g[7], g[11]};

    float* P = Pout + (size_t)i * 16;
    float pn = 0.0f;
#pragma unroll
    for (int c = 0; c < 5; ++c) {
        float cx = cp[c * 3], cy = cp[c * 3 + 1], cz = cp[c * 3 + 2];
#pragma unroll
        for (int ii = 0; ii < 3; ++ii) {
            float v = R[ii][0] * cx + R[ii][1] * cy + R[ii][2] * cz + t[ii];
            P[c * 3 + ii] = v;
            pn += v * v;
        }
    }
    P[15] = pn;

    bool succ = d2w[i] < R2_;
    int j = idxw[i];
    float RL[3][3], TL[3];
    if (succ) {
        const float* rl = rot + ((size_t)b * M_ + j) * 9;
#pragma unroll
        for (int a = 0; a < 3; ++a)
#pragma unroll
            for (int bb = 0; bb < 3; ++bb) RL[a][bb] = rl[a * 3 + bb];
        const float* tl = trans + ((size_t)b * M_ + j) * 3;
        TL[0] = tl[0]; TL[1] = tl[1]; TL[2] = tl[2];
    } else {
#pragma unroll
        for (int a = 0; a < 3; ++a) {
#pragma unroll
            for (int bb = 0; bb < 3; ++bb) RL[a][bb] = FAR_;
            TL[a] = FAR_;
        }
    }

    float* G = Gout + (size_t)i * 32;
    float gn = 0.0f, gsn = 0.0f;
#pragma unroll
    for (int c = 0; c < 5; ++c) {
        float cx = cp[c * 3], cy = cp[c * 3 + 1], cz = cp[c * 3 + 2];
#pragma unroll
        for (int ii = 0; ii < 3; ++ii) {
            float v = RL[ii][0] * cx + RL[ii][1] * cy + RL[ii][2] * cz + TL[ii];
            G[c * 3 + ii] = v;
            gn += v * v;
        }
    }
    G[15] = gn;
#pragma unroll
    for (int c = 0; c < 5; ++c) {
        float cx = cps[c * 3], cy = cps[c * 3 + 1], cz = cps[c * 3 + 2];
#pragma unroll
        for (int ii = 0; ii < 3; ++ii) {
            float v = RL[ii][0] * cx + RL[ii][1] * cy + RL[ii][2] * cz + TL[ii];
            G[16 + c * 3 + ii] = v;
            gsn += v * v;
        }
    }
    G[31] = gsn;
}

// ---------------------------------------------------------------------------
// Kernel 3: ADD-S min: m[b,i] = min_j min(|P_i - G_j|^2, |P_i - Gs_j|^2)
// Grid = B * (N/8) = 1024 blocks. Block = 4 i-groups (2 i each) x 64 j-parts (32 j each).
// Each thread register-blocks 2 i's: one 32-float G read feeds 60 FMAs.
__global__ void adds_kernel(const float* __restrict__ Parr, const float* __restrict__ Garr,
                            float* __restrict__ mOut) {
    int blk = blockIdx.x;                  // B * (N/8)
    int b = blk / (N_ / 8);
    int tile = blk % (N_ / 8);
    int ig = threadIdx.x & 3;              // i-group: 2 consecutive i's
    int part = threadIdx.x >> 2;           // 0..63 j partitions
    int i0 = tile * 8 + ig * 2;

    const float4* P4 = reinterpret_cast<const float4*>(Parr) + ((size_t)b * N_ + i0) * 4;
    float Pa[16], Pb[16];
#pragma unroll
    for (int q = 0; q < 4; ++q) {
        float4 t4 = P4[q];
        Pa[q * 4 + 0] = t4.x; Pa[q * 4 + 1] = t4.y; Pa[q * 4 + 2] = t4.z; Pa[q * 4 + 3] = t4.w;
    }
#pragma unroll
    for (int q = 0; q < 4; ++q) {
        float4 t4 = P4[4 + q];
        Pb[q * 4 + 0] = t4.x; Pb[q * 4 + 1] = t4.y; Pb[q * 4 + 2] = t4.z; Pb[q * 4 + 3] = t4.w;
    }
    float pna = Pa[15], pnb = Pb[15];

    const float4* Gb4 = reinterpret_cast<const float4*>(Garr) + (size_t)b * N_ * 8;
    float besta = INFINITY, bestb = INFINITY;
    int j0 = part * (N_ / 64);
    for (int j = j0; j < j0 + (N_ / 64); ++j) {
        const float4* G4 = Gb4 + (size_t)j * 8;
        float gg[32];
#pragma unroll
        for (int q = 0; q < 8; ++q) {
            float4 t4 = G4[q];
            gg[q * 4 + 0] = t4.x; gg[q * 4 + 1] = t4.y; gg[q * 4 + 2] = t4.z; gg[q * 4 + 3] = t4.w;
        }
        float da1 = 0.0f, da2 = 0.0f, db1 = 0.0f, db2 = 0.0f;
#pragma unroll
        for (int q = 0; q < 15; ++q) {
            da1 += Pa[q] * gg[q];
            db1 += Pb[q] * gg[q];
        }
#pragma unroll
        for (int q = 0; q < 15; ++q) {
            da2 += Pa[q] * gg[16 + q];
            db2 += Pb[q] * gg[16 + q];
        }
        float sa1 = pna + gg[15] - 2.0f * da1;
        float sa2 = pna + gg[31] - 2.0f * da2;
        float sb1 = pnb + gg[15] - 2.0f * db1;
        float sb2 = pnb + gg[31] - 2.0f * db2;
        besta = fminf(besta, fminf(sa1, sa2));
        bestb = fminf(bestb, fminf(sb1, sb2));
    }
    __shared__ float sm[64][8];
    sm[part][ig * 2 + 0] = besta;
    sm[part][ig * 2 + 1] = bestb;
    __syncthreads();
    if (threadIdx.x < 8) {
        float bb = sm[0][threadIdx.x];
#pragma unroll
        for (int q = 1; q < 64; ++q) bb = fminf(bb, sm[q][threadIdx.x]);
        mOut[b * N_ + tile * 8 + threadIdx.x] = bb;
    }
}

// ---------------------------------------------------------------------------
// Kernel 4: per-batch finalize — threefry r, hard-negative selection, all sums.
__global__ void finalize_kernel(const float* __restrict__ scores,
                                const float* __restrict__ gwh,
                                const float* __restrict__ pcw,
                                const int* __restrict__ idxw,
                                const float* __restrict__ d2w,
                                const float* __restrict__ mw,
                                float* __restrict__ batch_out) {
    int b = blockIdx.x;
    int tid = threadIdx.x;

    __shared__ float rlist[N_];
    __shared__ short neglist[N_];
    __shared__ unsigned char pos_sh[N_];
    __shared__ unsigned char sel_sh[N_];
    __shared__ int s_npos, s_ncnt;
    __shared__ float wsum[4][4];

    if (tid == 0) { s_npos = 0; s_ncnt = 0; }
    __syncthreads();

    int local_pos = 0;
    for (int n = tid; n < N_; n += 256) {
        bool pos = d2w[b * N_ + n] < R2_;
        pos_sh[n] = pos ? 1 : 0;
        sel_sh[n] = pos ? 1 : 0;
        float rr = jax_uniform_r(b * N_ + n);
        if (pos) {
            local_pos++;
        } else {
            int a = atomicAdd(&s_ncnt, 1);
            neglist[a] = (short)n;
            rlist[a] = rr;
        }
    }
    atomicAdd(&s_npos, local_pos);
    __syncthreads();

    int npos = s_npos;
    int ncnt = s_ncnt;
    int kk = (npos > 0) ? npos : 2;

    // rank each negative among negatives by r (stable tie-break on index)
    for (int a = tid; a < ncnt; a += 256) {
        float ra = rlist[a];
        int na = neglist[a];
        int cnt = 0;
        for (int q = 0; q < ncnt; ++q) {
            float rb = rlist[q];
            int nb = neglist[q];
            cnt += ((rb < ra) || (rb == ra && nb < na)) ? 1 : 0;
        }
        if (cnt < kk) sel_sh[na] = 1;
    }
    __syncthreads();

    float sum_sel = 0.0f, sum_bce = 0.0f, sum_wl = 0.0f, sum_adds = 0.0f;
    for (int n = tid; n < N_; n += 256) {
        float sc = scores[b * N_ + n];
        float pcl = fminf(fmaxf(sc, EPS_), 0.9999999f);
        bool pos = pos_sh[n] != 0;
        float s = pos ? 1.0f : 0.0f;
        float bce = -(s * logf(pcl) + (1.0f - s) * logf(1.0f - pcl));
        float selv = sel_sh[n] ? 1.0f : 0.0f;
        sum_sel += selv;
        sum_bce += bce * selv;
        if (pos) {
            int jx = idxw[b * N_ + n];
            float w = pcw[b * M_ + jx];
            float acc = 0.0f;
#pragma unroll
            for (int jb = 0; jb < 10; ++jb) {
                float x = gwh[((size_t)b * 10 + jb) * N_ + n];
                float mh = (w >= c_LO[jb] && w < c_HI[jb]) ? 1.0f : 0.0f;
                float bw = fmaxf(x, 0.0f) - x * mh + log1pf(expf(-fabsf(x)));
                acc += c_BW[jb] * bw;
            }
            sum_wl += acc * 0.1f;
            float mv = mw[b * N_ + n];
            sum_adds += sc * sqrtf(fmaxf(mv, 0.0f) + 1e-12f);
        }
    }

    // deterministic reduce: wave shuffle + per-wave LDS + thread-0 combine
    float v0 = sum_sel, v1 = sum_bce, v2 = sum_wl, v3 = sum_adds;
#pragma unroll
    for (int off = 32; off > 0; off >>= 1) {
        v0 += __shfl_down(v0, off);
        v1 += __shfl_down(v1, off);
        v2 += __shfl_down(v2, off);
        v3 += __shfl_down(v3, off);
    }
    int wv = tid >> 6, lane = tid & 63;
    if (lane == 0) { wsum[wv][0] = v0; wsum[wv][1] = v1; wsum[wv][2] = v2; wsum[wv][3] = v3; }
    __syncthreads();
    if (tid == 0) {
        float t0 = 0, t1 = 0, t2 = 0, t3 = 0;
#pragma unroll
        for (int w = 0; w < 4; ++w) { t0 += wsum[w][0]; t1 += wsum[w][1]; t2 += wsum[w][2]; t3 += wsum[w][3]; }
        float piv = fmaxf((float)npos, 1.0f);       // pos_in_view
        float bin_ce_b = t1 / fmaxf(t0, 1.0f);
        float width_b = t2 / piv;
        float adds_b = t3 / piv;
        batch_out[b * 3 + 0] = bin_ce_b;
        batch_out[b * 3 + 1] = width_b;
        batch_out[b * 3 + 2] = adds_b;
    }
}

// ---------------------------------------------------------------------------
// Kernel 5: combine batches -> 4 outputs
__global__ void combine_kernel(const float* __restrict__ bv, float* __restrict__ out) {
    if (blockIdx.x == 0 && threadIdx.x == 0) {
        float bin = 0, wid = 0, ad = 0;
#pragma unroll
        for (int b = 0; b < B_; ++b) {
            bin += bv[b * 3 + 0];
            wid += bv[b * 3 + 1];
            ad += bv[b * 3 + 2];
        }
        bin *= 0.25f; wid *= 0.25f; ad *= 0.25f;
        out[0] = bin + wid + 3.0f * ad;
        out[1] = bin;
        out[2] = wid;
        out[3] = ad;
    }
}

// ---------------------------------------------------------------------------
extern "C" void kernel_launch(void* const* d_in, const int* in_sizes, int n_in,
                              void* d_out, int out_size, void* d_ws, size_t ws_size,
                              hipStream_t stream) {
    const float* pred_grasps = (const float*)d_in[0];   // (4,2048,4,4)
    const float* pred_scores = (const float*)d_in[1];   // (4,2048,1)
    const float* pred_points = (const float*)d_in[2];   // (4,2048,3)
    const float* gwh         = (const float*)d_in[3];   // (4,10,2048)
    const float* pcp         = (const float*)d_in[4];   // (4,4096,3)
    const float* pcw         = (const float*)d_in[5];   // (4,4096)
    const float* pcr         = (const float*)d_in[6];   // (4,4096,3,3)
    const float* pct         = (const float*)d_in[7];   // (4,4096,3)
    const float* cp          = (const float*)d_in[8];   // (1,5,3)
    const float* cps         = (const float*)d_in[9];   // (1,5,3)
    (void)in_sizes; (void)n_in; (void)out_size; (void)ws_size;

    float* ws = (float*)d_ws;
    float4* cpack = (float4*)ws;                        //  65536 floats
    int*   idxw = (int*)(ws + 65536);                   //   8192
    float* d2w  = ws + 65536 + 8192;                    //   8192
    float* Pw   = ws + 65536 + 16384;                   // 131072
    float* Gw   = Pw + 131072;                          // 262144
    float* mw   = Gw + 262144;                          //   8192
    float* bv   = mw + 8192;                            //     12
    float* outp = (float*)d_out;

    hipLaunchKernelGGL(pack_contacts, dim3((B_ * M_ + 255) / 256), dim3(256), 0, stream,
                       pcp, cpack);
    hipLaunchKernelGGL(nn_kernel, dim3(B_ * (N_ / 8)), dim3(256), 0, stream,
                       pred_points, cpack, idxw, d2w);
    hipLaunchKernelGGL(prep_kernel, dim3((B_ * N_ + 255) / 256), dim3(256), 0, stream,
                       pred_grasps, idxw, d2w, pcr, pct, cp, cps, Pw, Gw);
    hipLaunchKernelGGL(adds_kernel, dim3(B_ * (N_ / 8)), dim3(256), 0, stream,
                       Pw, Gw, mw);
    hipLaunchKernelGGL(finalize_kernel, dim3(B_), dim3(256), 0, stream,
                       pred_scores, gwh, pcw, idxw, d2w, mw, bv);
    hipLaunchKernelGGL(combine_kernel, dim3(1), dim3(64), 0, stream, bv, outp);
}